// Round 2
// baseline (435.280 us; speedup 1.0000x reference)
//
#include <hip/hip_runtime.h>
#include <hip/hip_bf16.h>

// Shapes fixed by the reference
#define T_TOK 4096
#define I1    512
#define O1    2049
#define K1    4608        // 8*512 spline + 512 silu (= 576 groups, no pad)
#define NG1   576         // K1/8
#define I2    2049
#define O2    512
#define K2    18560       // 8*2049 spline + 2049 silu + 119 pad = 2320 groups
#define NG2   2320        // K2/8
#define N1G   2048        // GEMM1 N (col 2048 handled by GEMV)
#define HPART ((size_t)T_TOK * N1G)   // one H partial, floats

typedef __attribute__((ext_vector_type(8))) short short8;
typedef __attribute__((ext_vector_type(4))) float floatx4;
typedef __attribute__((address_space(3))) void* lds_ptr_t;
typedef const __attribute__((address_space(1))) void* gmem_ptr_t;

__device__ __forceinline__ unsigned short f2bf(float f) {   // RNE (prep kernels)
  union { __hip_bfloat16 h; unsigned short u; } cv;
  cv.h = __float2bfloat16(f);
  return cv.u;
}
__device__ __forceinline__ float b2f(unsigned short u) {
  union { float f; unsigned u; } c; c.u = (unsigned)u << 16; return c.f;
}
__device__ __forceinline__ unsigned bfr(float f) {          // cheap near-RNE (expand hot path)
  union { float f; unsigned u; } c; c.f = f;
  return (c.u + 0x8000u) >> 16;
}
__device__ __forceinline__ float silu_f(float x) { return x / (1.0f + __expf(-x)); }

// All 8 cubic-basis slots for one group as 8 bf16 in a uint4 (branchless funnel shift).
__device__ __forceinline__ uint4 spline_pack(float h) {
  float u = (h + 2.2f) * 2.5f;
  int ji = (int)u;
  ji = ji < 0 ? 0 : (ji > 10 ? 10 : ji);
  float t = u - (float)ji;
  float it = 1.0f - t, t2 = t * t, t3 = t2 * t;
  float b0 = it * it * it * (1.0f / 6.0f);
  float b1 = (3.0f * t3 - 6.0f * t2 + 4.0f) * (1.0f / 6.0f);
  float b2 = (-3.0f * t3 + 3.0f * t2 + 3.0f * t + 1.0f) * (1.0f / 6.0f);
  float b3 = t3 * (1.0f / 6.0f);
  unsigned pk01 = bfr(b0) | (bfr(b1) << 16);
  unsigned pk23 = bfr(b2) | (bfr(b3) << 16);
  unsigned long long p64 = (unsigned long long)pk01 | ((unsigned long long)pk23 << 32);
  bool inR = (h >= -2.2f) && (h < 2.2f);
  p64 = inR ? p64 : 0ull;
  int sh = (ji - 3) * 16;
  int shr = sh < 0 ? -sh : 0;
  int shl = sh < 0 ? 0 : sh;
  __uint128_t v = ((__uint128_t)(p64 >> shr)) << shl;
  union { __uint128_t q; uint4 u4; } cv;
  cv.q = v;
  return cv.u4;
}

// W1'[o,k]: k<4096 -> spline_w1[o,k>>3,k&7]*scaler1[o,k>>3]; else base_w1. o < 2049.
__global__ void pack_w1_kernel(const float* __restrict__ bw, const float* __restrict__ sw,
                               const float* __restrict__ sc, unsigned short* __restrict__ W) {
  int k = blockIdx.x * 256 + threadIdx.x;  // grid exact: 18*256 = 4608
  int o = blockIdx.y;                      // < 2049
  float v;
  if (k < 4096) v = sw[(size_t)o * 4096 + k] * sc[(size_t)o * I1 + (k >> 3)];
  else          v = bw[(size_t)o * I1 + (k - 4096)];
  W[(size_t)o * K1 + k] = f2bf(v);
}

// W2'[o,k]: k<16392 -> spline_w2*scaler2; k<18441 -> base_w2; else 0
__global__ void pack_w2_kernel(const float* __restrict__ bw, const float* __restrict__ sw,
                               const float* __restrict__ sc, unsigned short* __restrict__ W) {
  int k = blockIdx.x * 256 + threadIdx.x;
  if (k >= K2) return;
  int o = blockIdx.y;                      // < 512
  float v = 0.0f;
  if (k < 16392)      v = sw[(size_t)o * 16392 + k] * sc[(size_t)o * I2 + (k >> 3)];
  else if (k < 18441) v = bw[(size_t)o * I2 + (k - 16392)];
  W[(size_t)o * K2 + k] = f2bf(v);
}

// A1[m, g*8..g*8+7]: g<512 -> spline basis of x[m,g]; g>=512 -> silu(x[m, (g-512)*8 + c]).
__global__ void expand1_kernel(const float* __restrict__ x, unsigned short* __restrict__ A) {
  int g = blockIdx.x * 256 + threadIdx.x;
  if (g >= NG1) return;
  int m = blockIdx.y;
  uint4 val;
  if (g < 512) {
    val = spline_pack(x[(size_t)m * I1 + g]);
  } else {
    const float4* xr = (const float4*)(x + (size_t)m * I1 + (size_t)(g - 512) * 8);
    float4 a = xr[0], b = xr[1];
    union { unsigned short s[8]; uint4 v; } pk;
    pk.s[0] = f2bf(silu_f(a.x)); pk.s[1] = f2bf(silu_f(a.y));
    pk.s[2] = f2bf(silu_f(a.z)); pk.s[3] = f2bf(silu_f(a.w));
    pk.s[4] = f2bf(silu_f(b.x)); pk.s[5] = f2bf(silu_f(b.y));
    pk.s[6] = f2bf(silu_f(b.z)); pk.s[7] = f2bf(silu_f(b.w));
    val = pk.v;
  }
  *(uint4*)(A + (size_t)m * K1 + (size_t)g * 8) = val;
}

// GEMV: H[:,2048] = A1 @ W1'[2048,:]^T. One wave per row m; 4608 = 9*64 groups of 8.
__global__ void gemv_col_kernel(const unsigned short* __restrict__ A1,
                                const unsigned short* __restrict__ W1,
                                float* __restrict__ Hcol) {
  int m = blockIdx.x * 4 + (threadIdx.x >> 6);
  int lane = threadIdx.x & 63;
  const unsigned short* a  = A1 + (size_t)m * K1;
  const unsigned short* wr = W1 + (size_t)2048 * K1;
  float s = 0.0f;
#pragma unroll
  for (int c = 0; c < 9; ++c) {
    int off = (c * 64 + lane) * 8;
    short8 av = *(const short8*)(a + off);
    short8 wv = *(const short8*)(wr + off);
#pragma unroll
    for (int j = 0; j < 8; ++j)
      s += b2f((unsigned short)av[j]) * b2f((unsigned short)wv[j]);
  }
#pragma unroll
  for (int d = 32; d >= 1; d >>= 1) s += __shfl_down(s, d);
  if (lane == 0) Hcol[m] = s;
}

// A2 from H = Ha + Hb (split-K partials) with H[:,2048] in Hcol.
// g<2049 -> spline; 2049<=g<2306 -> silu (idx guard); else 0.
__global__ void expand2_kernel(const float* __restrict__ Ha, const float* __restrict__ Hb,
                               const float* __restrict__ Hcol, unsigned short* __restrict__ A) {
  int g = blockIdx.x * 256 + threadIdx.x;
  if (g >= NG2) return;
  int m = blockIdx.y;
  float hc = Hcol[m];
  uint4 val;
  if (g < 2049) {
    float h = (g < N1G) ? Ha[(size_t)m * N1G + g] + Hb[(size_t)m * N1G + g] : hc;
    val = spline_pack(h);
  } else if (g < 2306) {
    int c0 = (g - 2049) * 8;
    union { unsigned short s[8]; uint4 v; } pk;
#pragma unroll
    for (int c = 0; c < 8; ++c) {
      int idx = c0 + c;
      float v = 0.0f;
      if (idx < I2) {
        float h = (idx < N1G) ? Ha[(size_t)m * N1G + idx] + Hb[(size_t)m * N1G + idx] : hc;
        v = silu_f(h);
      }
      pk.s[c] = f2bf(v);
    }
    val = pk.v;
  } else {
    val = make_uint4(0u, 0u, 0u, 0u);
  }
  *(uint4*)(A + (size_t)m * K2 + (size_t)g * 8) = val;
}

// ---- 256x256 phase-split GEMM (T2+T3+T4+T5) ----
// C = A(MxK) * B(NxK)^T, bf16, 512 threads = 8 waves (2M x 4N), per-wave 128x64.
// BK=64, 2-deep LDS (128 KiB), XOR-chunk swizzle (verified 0-conflict).
// 4 phases/K-tile: (kk0,mh0)+stageA(t+1), (kk0,mh1)+stageB(t+1), (kk1,mh0), (kk1,mh1)+vmcnt(0).
// Stages front-loaded in ph0/ph1 -> the ph3 drain waits on loads issued ~2-3 phases
// (~500cy) earlier; with L2/L3-resident sources the drain is near-free (vs. the
// 2-barrier structure's full-latency stall every K-tile).
// Raw s_barrier (asm, memory clobber); lgkmcnt(0)+sched_barrier(0) per rule #18.
// Grid: exactly 256 blocks (1/CU). XCD-bijective decode (nwg%8==0).
__device__ __forceinline__ void BARv() { asm volatile("s_barrier" ::: "memory"); }
__device__ __forceinline__ void LGKM0() {
  asm volatile("s_waitcnt lgkmcnt(0)" ::: "memory");
  __builtin_amdgcn_sched_barrier(0);
}
__device__ __forceinline__ void VM0() { asm volatile("s_waitcnt vmcnt(0)" ::: "memory"); }

__device__ __forceinline__ void read_af(short8* af, const unsigned short* Asp,
                                        int wmh, int mh, int kk, int q, int ln) {
#pragma unroll
  for (int j = 0; j < 4; ++j) {
    int rr = wmh * 128 + (mh * 4 + j) * 16 + ln;
    int cl = (kk * 4 + q) ^ (rr & 7);
    af[j] = *(const short8*)&Asp[rr * 64 + cl * 8];
  }
}
__device__ __forceinline__ void read_bf(short8* bf, const unsigned short* Bsp,
                                        int wnq, int kk, int q, int ln) {
#pragma unroll
  for (int n = 0; n < 4; ++n) {
    int rb = wnq * 64 + n * 16 + ln;
    int cl = (kk * 4 + q) ^ (rb & 7);
    bf[n] = *(const short8*)&Bsp[rb * 64 + cl * 8];
  }
}

__global__ __launch_bounds__(512, 2)
void gemm256_kernel(const unsigned short* __restrict__ Aw, const unsigned short* __restrict__ Bw,
                    float* __restrict__ C, int Ktot, int kStep, int nBx, int nBz,
                    int ldc, size_t pslice, int storeMode)
{
  __shared__ __align__(16) unsigned short As[2][256 * 64];
  __shared__ __align__(16) unsigned short Bs[2][256 * 64];

  // XCD-bijective swizzle for 256 blocks, then (bx, by, bz)
  const int Lb = blockIdx.x;
  const int wgid = (Lb & 7) * 32 + (Lb >> 3);
  const int bx = wgid % nBx;
  const int tq = wgid / nBx;
  const int by = tq & 15;
  const int bz = tq >> 4;

  const int tid = threadIdx.x;
  const int ks = bz * kStep;
  const int ke = (bz == nBz - 1) ? Ktot : ks + kStep;
  const int ntiles = (ke - ks) >> 6;

  const int w = tid >> 6, L = tid & 63, q = L >> 4, ln = L & 15;
  const int wmh = w & 1;         // M half (128 rows)
  const int wnq = w >> 1;        // N quarter (64 cols)

  floatx4 zf = {0.f, 0.f, 0.f, 0.f};
  floatx4 acc[8][4];
#pragma unroll
  for (int f = 0; f < 8; ++f)
#pragma unroll
    for (int n = 0; n < 4; ++n)
      acc[f][n] = zf;

  // Staging: 4 chunks/thread/operand/K-tile; linear LDS dest, XOR-swizzled source.
  const unsigned short* gA[4];
  const unsigned short* gB[4];
  int ldsO[4];
#pragma unroll
  for (int l = 0; l < 4; ++l) {
    int e = l * 512 + tid;
    int br = e >> 3;
    int cg = (e & 7) ^ (br & 7);
    gA[l] = Aw + ((size_t)(by * 256 + br)) * Ktot + ks + cg * 8;
    gB[l] = Bw + ((size_t)(bx * 256 + br)) * Ktot + ks + cg * 8;
    ldsO[l] = e * 8;
  }

  // Prologue: stage tile 0 into buf 0, full drain once.
  {
    unsigned short* Asn = (unsigned short*)As[0];
    unsigned short* Bsn = (unsigned short*)Bs[0];
#pragma unroll
    for (int l = 0; l < 4; ++l) {
      __builtin_amdgcn_global_load_lds((gmem_ptr_t)gA[l], (lds_ptr_t)&Asn[ldsO[l]], 16, 0, 0);
      gA[l] += 64;
      __builtin_amdgcn_global_load_lds((gmem_ptr_t)gB[l], (lds_ptr_t)&Bsn[ldsO[l]], 16, 0, 0);
      gB[l] += 64;
    }
  }
  VM0(); BARv();

  for (int t = 0; t < ntiles; ++t) {
    unsigned short* Asp = (unsigned short*)As[t & 1];
    unsigned short* Bsp = (unsigned short*)Bs[t & 1];
    unsigned short* Asn = (unsigned short*)As[(t & 1) ^ 1];
    unsigned short* Bsn = (unsigned short*)Bs[(t & 1) ^ 1];
    const bool pf = (t + 1 < ntiles);
    short8 af[4], bf[4];

    // ---- phase 0: bf(kk0), af(mh0,kk0); stage A(t+1) ----
    read_bf(bf, Bsp, wnq, 0, q, ln);
    read_af(af, Asp, wmh, 0, 0, q, ln);
    if (pf) {
#pragma unroll
      for (int l = 0; l < 4; ++l) {
        __builtin_amdgcn_global_load_lds((gmem_ptr_t)gA[l], (lds_ptr_t)&Asn[ldsO[l]], 16, 0, 0);
        gA[l] += 64;
      }
    }
    BARv(); LGKM0();
    __builtin_amdgcn_s_setprio(1);
#pragma unroll
    for (int j = 0; j < 4; ++j)
#pragma unroll
      for (int n = 0; n < 4; ++n)
        acc[j][n] = __builtin_amdgcn_mfma_f32_16x16x32_bf16(af[j], bf[n], acc[j][n], 0, 0, 0);
    __builtin_amdgcn_s_setprio(0);
    BARv();

    // ---- phase 1: af(mh1,kk0); stage B(t+1) ----
    read_af(af, Asp, wmh, 1, 0, q, ln);
    if (pf) {
#pragma unroll
      for (int l = 0; l < 4; ++l) {
        __builtin_amdgcn_global_load_lds((gmem_ptr_t)gB[l], (lds_ptr_t)&Bsn[ldsO[l]], 16, 0, 0);
        gB[l] += 64;
      }
    }
    BARv(); LGKM0();
    __builtin_amdgcn_s_setprio(1);
#pragma unroll
    for (int j = 0; j < 4; ++j)
#pragma unroll
      for (int n = 0; n < 4; ++n)
        acc[4 + j][n] = __builtin_amdgcn_mfma_f32_16x16x32_bf16(af[j], bf[n], acc[4 + j][n], 0, 0, 0);
    __builtin_amdgcn_s_setprio(0);
    BARv();

    // ---- phase 2: bf(kk1), af(mh0,kk1) ----
    read_bf(bf, Bsp, wnq, 1, q, ln);
    read_af(af, Asp, wmh, 0, 1, q, ln);
    BARv(); LGKM0();
    __builtin_amdgcn_s_setprio(1);
#pragma unroll
    for (int j = 0; j < 4; ++j)
#pragma unroll
      for (int n = 0; n < 4; ++n)
        acc[j][n] = __builtin_amdgcn_mfma_f32_16x16x32_bf16(af[j], bf[n], acc[j][n], 0, 0, 0);
    __builtin_amdgcn_s_setprio(0);
    BARv();

    // ---- phase 3: af(mh1,kk1); counted drain (stages are 2-3 phases old) ----
    read_af(af, Asp, wmh, 1, 1, q, ln);
    BARv(); LGKM0();
    __builtin_amdgcn_s_setprio(1);
#pragma unroll
    for (int j = 0; j < 4; ++j)
#pragma unroll
      for (int n = 0; n < 4; ++n)
        acc[4 + j][n] = __builtin_amdgcn_mfma_f32_16x16x32_bf16(af[j], bf[n], acc[4 + j][n], 0, 0, 0);
    __builtin_amdgcn_s_setprio(0);
    VM0();   // t+1's A/B fully landed before the publish barrier
    BARv();
  }

  // Epilogue. D layout: col = lane&15 (n), row = q*4+reg (m)  [m89-verified]
  const int gmb = by * 256 + wmh * 128 + q * 4;
  const int gnb = bx * 256 + wnq * 64 + ln;
  if (storeMode == 0) {                     // plain store into split-K partial (layer 1)
    float* Cp = C + (size_t)bz * pslice;
#pragma unroll
    for (int f = 0; f < 8; ++f)
#pragma unroll
      for (int n = 0; n < 4; ++n)
#pragma unroll
        for (int rg = 0; rg < 4; ++rg)
          Cp[(size_t)(gmb + f * 16 + rg) * ldc + (gnb + n * 16)] = acc[f][n][rg];
  } else {                                  // atomic accumulate (layer 2, split-K 8)
#pragma unroll
    for (int f = 0; f < 8; ++f)
#pragma unroll
      for (int n = 0; n < 4; ++n)
#pragma unroll
        for (int rg = 0; rg < 4; ++rg)
          atomicAdd(&C[(size_t)(gmb + f * 16 + rg) * ldc + (gnb + n * 16)], acc[f][n][rg]);
  }
}

extern "C" void kernel_launch(void* const* d_in, const int* in_sizes, int n_in,
                              void* d_out, int out_size, void* d_ws, size_t ws_size,
                              hipStream_t stream) {
  const float* x   = (const float*)d_in[0];
  const float* bw1 = (const float*)d_in[1];
  const float* sw1 = (const float*)d_in[2];
  const float* sc1 = (const float*)d_in[3];
  const float* bw2 = (const float*)d_in[4];
  const float* sw2 = (const float*)d_in[5];
  const float* sc2 = (const float*)d_in[6];
  float* out = (float*)d_out;

  // Workspace: Ha(33.6) | Hb(33.6) | Hcol(64KB) | W2(19.0) | A2(152.0; A1 37.7 + W1 18.9 aliased)
  // Total ~238 MB. A1/W1 die at gemm1+gemv; expand2 overwrites (stream-ordered).
  float* Ha = (float*)d_ws;
  float* Hb = Ha + HPART;
  float* Hcol = Hb + HPART;
  unsigned short* W2 = (unsigned short*)(Hcol + 16384);
  unsigned short* A2 = W2 + (size_t)O2 * K2;
  unsigned short* A1 = A2;                              // alias (first 37.7 MB)
  unsigned short* W1 = A1 + (size_t)T_TOK * K1;         // next 18.9 MB

  hipMemsetAsync(d_out, 0, (size_t)out_size * sizeof(float), stream);

  pack_w1_kernel<<<dim3(K1 / 256, O1), 256, 0, stream>>>(bw1, sw1, sc1, W1);
  pack_w2_kernel<<<dim3((K2 + 255) / 256, O2), 256, 0, stream>>>(bw2, sw2, sc2, W2);
  expand1_kernel<<<dim3((NG1 + 255) / 256, T_TOK), 256, 0, stream>>>(x, A1);

  // H column 2048 via GEMV (keeps the big GEMM at N=2048 exactly -> 256 blocks)
  gemv_col_kernel<<<T_TOK / 4, 256, 0, stream>>>(A1, W1, Hcol);

  // Layer 1: Ha/Hb = A1 @ W1'^T. M=4096, N=2048, K=4608; 16x8 spatial x split-K 2 = 256 blocks.
  gemm256_kernel<<<256, 512, 0, stream>>>(A1, W1, Ha, K1, 2304, 8, 2, N1G, HPART, 0);

  expand2_kernel<<<dim3((NG2 + 255) / 256, T_TOK), 256, 0, stream>>>(Ha, Hb, Hcol, A2);

  // Layer 2: out += A2 @ W2'^T. M=4096, N=512, K=18560; 16x2 spatial x split-K 8 = 256 blocks.
  gemm256_kernel<<<256, 512, 0, stream>>>(A2, W2, out, K2, 2304, 2, 8, O2, 0, 2);
}